// Round 11
// baseline (217.912 us; speedup 1.0000x reference)
//
#include <hip/hip_runtime.h>

#define C 128
#define LDSPAD 136  // padded LDS row stride (ushorts); 272B rows, 16B-aligned
#define CAP 64      // padded-CSR slots per node (mean deg 20, Poisson tail < 1e-13)

typedef unsigned int uint;
typedef unsigned short ushort;
typedef __attribute__((ext_vector_type(8))) short bf16x8;
typedef __attribute__((ext_vector_type(4))) float f32x4;
typedef __attribute__((ext_vector_type(4))) float nf4;  // nontemporal-capable float4

__device__ __forceinline__ float bf_lo(uint u) { return __uint_as_float(u << 16); }
__device__ __forceinline__ float bf_hi(uint u) { return __uint_as_float(u & 0xffff0000u); }
__device__ __forceinline__ uint f2bf(float f) {
  uint u = __float_as_uint(f);
  return (u + 0x7fffu + ((u >> 16) & 1u)) >> 16;  // RNE, no NaN inputs
}
__device__ __forceinline__ uint pk2(float a, float b) {
  return f2bf(a) | (f2bf(b) << 16);
}

// ---------------- Kernel 1: prep — emb->bf16 (nt load), 4 weights->bf16, zero cnt ----------
__global__ __launch_bounds__(256) void k_prep(
    const float* __restrict__ emb, ushort4* __restrict__ embh, int n4,
    const float4* __restrict__ w0, const float4* __restrict__ w1,
    const float4* __restrict__ w2, const float4* __restrict__ w3,
    ushort4* __restrict__ wb, int nw4each,
    int4* __restrict__ zb, int nz4) {
  int i = blockIdx.x * blockDim.x + threadIdx.x;
  if (i < n4) {
    nf4 f = __builtin_nontemporal_load((const nf4*)emb + i);
    ushort4 o = {(ushort)f2bf(f.x), (ushort)f2bf(f.y), (ushort)f2bf(f.z), (ushort)f2bf(f.w)};
    embh[i] = o;
  }
  if (i < 4 * nw4each) {
    int m = i / nw4each;
    int j = i - m * nw4each;
    const float4* w = (m == 0) ? w0 : (m == 1) ? w1 : (m == 2) ? w2 : w3;
    float4 f = w[j];
    ushort4 o = {(ushort)f2bf(f.x), (ushort)f2bf(f.y), (ushort)f2bf(f.z), (ushort)f2bf(f.w)};
    wb[i] = o;
  }
  if (i < nz4) {
    int4 z = {0, 0, 0, 0};
    zb[i] = z;
  }
}

// LayerNorm+ReLU for ONE node over 8-channels-per-lane layout (lane c holds ch
// c*8..c*8+7, duplicated across the 4 grps) and packed uint4 store.
__device__ __forceinline__ void ln_relu_store(const float s[8], float4 ga, float4 gb,
                                              float4 ba, float4 bb, ushort* hrow, int c) {
  float loc = ((s[0] + s[1]) + (s[2] + s[3])) + ((s[4] + s[5]) + (s[6] + s[7]));
#pragma unroll
  for (int off = 8; off; off >>= 1) loc += __shfl_xor(loc, off, 64);
  float mu = loc * (1.f / C);
  float d[8];
  float sq = 0.f;
#pragma unroll
  for (int j = 0; j < 8; ++j) {
    d[j] = s[j] - mu;
    sq += d[j] * d[j];
  }
#pragma unroll
  for (int off = 8; off; off >>= 1) sq += __shfl_xor(sq, off, 64);
  float rs = rsqrtf(sq * (1.f / C) + 1e-5f);
  float o0 = fmaxf(d[0] * rs * ga.x + ba.x, 0.f);
  float o1 = fmaxf(d[1] * rs * ga.y + ba.y, 0.f);
  float o2 = fmaxf(d[2] * rs * ga.z + ba.z, 0.f);
  float o3 = fmaxf(d[3] * rs * ga.w + ba.w, 0.f);
  float o4 = fmaxf(d[4] * rs * gb.x + bb.x, 0.f);
  float o5 = fmaxf(d[5] * rs * gb.y + bb.y, 0.f);
  float o6 = fmaxf(d[6] * rs * gb.z + bb.z, 0.f);
  float o7 = fmaxf(d[7] * rs * gb.w + bb.w, 0.f);
  uint4 o = {pk2(o0, o1), pk2(o2, o3), pk2(o4, o5), pk2(o6, o7)};
  *(uint4*)(hrow + c * 8) = o;
}

// ---------------- Kernel 2: embed+LN+ReLU with INTERLEAVED bucket blocks (R10 best) -------
__global__ __launch_bounds__(256) void k_embed_bkt(
    const int* __restrict__ x, const ushort* __restrict__ emb,
    const float* __restrict__ g, const float* __restrict__ b,
    ushort* __restrict__ h, int n0,
    const int* __restrict__ src1, const int* __restrict__ dst1,
    int* __restrict__ cnt1, int* __restrict__ slots1, int e1,
    const int* __restrict__ src2, const int* __restrict__ dst2,
    int* __restrict__ cnt2, int* __restrict__ slots2, int e2,
    int bktBlocks, int totBlocks) {
  uint bid = blockIdx.x;
  // Bresenham spread: f(b) = floor(b*bktBlocks/totBlocks); block b is a bucket
  // block iff f(b+1) > f(b); bucket index = f(b); embed index = b - f(b).
  uint f0 = (bid * (uint)bktBlocks) / (uint)totBlocks;
  uint f1 = ((bid + 1u) * (uint)bktBlocks) / (uint)totBlocks;
  if (f1 > f0) {
    int base = (int)f0 * 512 + (int)threadIdx.x;
#pragma unroll
    for (int r = 0; r < 2; ++r) {
      int i = base + r * 256;
      if (i < e1) {
        int d = __builtin_nontemporal_load(&dst1[i]);
        int s = __builtin_nontemporal_load(&src1[i]);
        int p = atomicAdd(&cnt1[d], 1);
        if (p < CAP) __builtin_nontemporal_store(s, &slots1[d * CAP + p]);
      } else if (i < e1 + e2) {
        int j = i - e1;
        int d = __builtin_nontemporal_load(&dst2[j]);
        int s = __builtin_nontemporal_load(&src2[j]);
        int p = atomicAdd(&cnt2[d], 1);
        if (p < CAP) __builtin_nontemporal_store(s, &slots2[d * CAP + p]);
      }
    }
    return;
  }
  int eb = (int)(bid - f0);
  int wid = threadIdx.x >> 6;
  int lane = threadIdx.x & 63;
  int grp = lane >> 4;  // 0..3: token-subgroup, later the node this lane stores
  int c = lane & 15;    // channel-16th: lane covers ch c*8..c*8+7
  int node0 = (eb * 4 + wid) * 4;  // 4 consecutive nodes per wave
  if (node0 >= n0) return;         // n0 % 16 == 0: no intra-wave tail
  int xv0 = __builtin_nontemporal_load(&x[(size_t)(node0 + 0) * 16 + c]);
  int xv1 = __builtin_nontemporal_load(&x[(size_t)(node0 + 1) * 16 + c]);
  int xv2 = __builtin_nontemporal_load(&x[(size_t)(node0 + 2) * 16 + c]);
  int xv3 = __builtin_nontemporal_load(&x[(size_t)(node0 + 3) * 16 + c]);
  float s[4][8];
#pragma unroll
  for (int n = 0; n < 4; ++n)
#pragma unroll
    for (int j = 0; j < 8; ++j) s[n][j] = 0.f;
#pragma unroll
  for (int w = 0; w < 4; ++w) {
    int t0 = __shfl(xv0, w * 4 + grp, 64);
    int t1 = __shfl(xv1, w * 4 + grp, 64);
    int t2 = __shfl(xv2, w * 4 + grp, 64);
    int t3 = __shfl(xv3, w * 4 + grp, 64);
    uint4 u0 = ((const uint4*)(emb + (size_t)t0 * C))[c];
    uint4 u1 = ((const uint4*)(emb + (size_t)t1 * C))[c];
    uint4 u2 = ((const uint4*)(emb + (size_t)t2 * C))[c];
    uint4 u3 = ((const uint4*)(emb + (size_t)t3 * C))[c];
    s[0][0] += bf_lo(u0.x); s[0][1] += bf_hi(u0.x);
    s[0][2] += bf_lo(u0.y); s[0][3] += bf_hi(u0.y);
    s[0][4] += bf_lo(u0.z); s[0][5] += bf_hi(u0.z);
    s[0][6] += bf_lo(u0.w); s[0][7] += bf_hi(u0.w);
    s[1][0] += bf_lo(u1.x); s[1][1] += bf_hi(u1.x);
    s[1][2] += bf_lo(u1.y); s[1][3] += bf_hi(u1.y);
    s[1][4] += bf_lo(u1.z); s[1][5] += bf_hi(u1.z);
    s[1][6] += bf_lo(u1.w); s[1][7] += bf_hi(u1.w);
    s[2][0] += bf_lo(u2.x); s[2][1] += bf_hi(u2.x);
    s[2][2] += bf_lo(u2.y); s[2][3] += bf_hi(u2.y);
    s[2][4] += bf_lo(u2.z); s[2][5] += bf_hi(u2.z);
    s[2][6] += bf_lo(u2.w); s[2][7] += bf_hi(u2.w);
    s[3][0] += bf_lo(u3.x); s[3][1] += bf_hi(u3.x);
    s[3][2] += bf_lo(u3.y); s[3][3] += bf_hi(u3.y);
    s[3][4] += bf_lo(u3.z); s[3][5] += bf_hi(u3.z);
    s[3][6] += bf_lo(u3.w); s[3][7] += bf_hi(u3.w);
  }
  // combine the 4 token-subgroups: every lane ends with all 4 nodes' full sums
#pragma unroll
  for (int n = 0; n < 4; ++n)
#pragma unroll
    for (int j = 0; j < 8; ++j) {
      s[n][j] += __shfl_xor(s[n][j], 16, 64);
      s[n][j] += __shfl_xor(s[n][j], 32, 64);
    }
  // per-grp epilogue: grp g handles node g (static ?: selection — rule #20)
  float sel[8];
#pragma unroll
  for (int j = 0; j < 8; ++j)
    sel[j] = (grp == 0) ? s[0][j] : (grp == 1) ? s[1][j] : (grp == 2) ? s[2][j] : s[3][j];
  float4 ga = ((const float4*)g)[c * 2];
  float4 gb = ((const float4*)g)[c * 2 + 1];
  float4 ba = ((const float4*)b)[c * 2];
  float4 bb = ((const float4*)b)[c * 2 + 1];
  ln_relu_store(sel, ga, gb, ba, bb, h + (size_t)(node0 + grp) * C, c);
}

// ---------------- Kernel 3/4: fused conv = aggregate(mean) + MFMA combine ----------------
// block = 512 (8 waves) -> 32 target nodes (TWO 16-node batches per block).
// Straggler fix: block Phase-A time was max over 16 single-node half-waves
// (E[max16 Poisson20 ceil8] ~ 40 vs mean 24); with 2 sequential nodes per half-wave
// the per-wave sums average out (stretch ~1.65x -> ~1.3x), and block count halves
// (sync + launch-tail cost halves).
// Phase B: wave w computes n-tile w for BOTH row-halves; wl/wr fragments loaded once
// feed both halves' MFMAs (16 MFMA, 8 weight loads).
// C/D layout: lane,reg -> out[mrow + (lane>>4)*4 + reg][nbase + (lane&15)]  [m89-verified]
template <bool RELU, bool BF16OUT>
__global__ __launch_bounds__(512) void k_conv(
    const int* __restrict__ cntArr, const int* __restrict__ slots,
    const ushort* __restrict__ h, const ushort* __restrict__ Wlb,
    const float* __restrict__ bl, const ushort* __restrict__ Wrb,
    void* __restrict__ outp, int ntgt) {
  __shared__ __align__(16) ushort smean[32 * LDSPAD];
  int wave = threadIdx.x >> 6;
  int lane = threadIdx.x & 63;
  int grp = lane >> 5, sub = lane & 31;
  int mbase = blockIdx.x * 32;
  int half = grp * 32;
  int l16 = (lane >> 4) & 1;  // which 16-lane group within the half-wave
  int c = lane & 15;          // lane covers ch c*8..c*8+7 of its edge's row

  // ---- Phase A: two 16-node batches, sequential per half-wave ----
#pragma unroll
  for (int t = 0; t < 2; ++t) {
    int nl = wave * 2 + grp;
    int node = mbase + t * 16 + nl;
    int truecnt = (node < ntgt) ? cntArr[node] : 0;
    int cnt = min(truecnt, CAP);
    const int* sl = slots + (size_t)(node < ntgt ? node : 0) * CAP;
    int ev = (sub < cnt) ? sl[sub] : 0;
    int ev2 = (sub + 32 < cnt) ? sl[sub + 32] : 0;
    int dmax = max(cnt, __shfl_xor(cnt, 32, 64));
    float s[8];
#pragma unroll
    for (int j = 0; j < 8; ++j) s[j] = 0.f;
    for (int d = 0; d < dmax; d += 8) {
#pragma unroll
      for (int k = 0; k < 4; ++k) {
        int p = d + 2 * k + l16;
        int e = (p < 32) ? __shfl(ev, half + p, 64) : __shfl(ev2, half + p - 32, 64);
        uint4 u = ((const uint4*)(h + (size_t)e * C))[c];
        uint msk = (p < cnt) ? 0xffffffffu : 0u;
        u.x &= msk; u.y &= msk; u.z &= msk; u.w &= msk;
        s[0] += bf_lo(u.x); s[1] += bf_hi(u.x);
        s[2] += bf_lo(u.y); s[3] += bf_hi(u.y);
        s[4] += bf_lo(u.z); s[5] += bf_hi(u.z);
        s[6] += bf_lo(u.w); s[7] += bf_hi(u.w);
      }
    }
    // combine the two 16-lane halves (each summed a disjoint set of edges)
#pragma unroll
    for (int j = 0; j < 8; ++j) s[j] += __shfl_xor(s[j], 16, 64);
    float sc = 1.f / (float)max(truecnt, 1);
    uint4 o = {pk2(s[0] * sc, s[1] * sc), pk2(s[2] * sc, s[3] * sc),
               pk2(s[4] * sc, s[5] * sc), pk2(s[6] * sc, s[7] * sc)};
    if (l16 == 0) *(uint4*)(smean + (t * 16 + nl) * LDSPAD + c * 8) = o;
  }
  __syncthreads();

  // ---- Phase B: both row-halves, shared weight fragments ----
  int r16 = lane & 15;
  int quad = lane >> 4;
  int koff = quad * 8;
  bf16x8 am0[4], am1[4], ah0[4], ah1[4];
  int hr0 = min(mbase + r16, ntgt - 1);
  int hr1 = min(mbase + 16 + r16, ntgt - 1);
  const ushort* hrow0 = h + (size_t)hr0 * C;
  const ushort* hrow1 = h + (size_t)hr1 * C;
#pragma unroll
  for (int kc = 0; kc < 4; ++kc) {
    am0[kc] = *(const bf16x8*)(smean + r16 * LDSPAD + kc * 32 + koff);
    am1[kc] = *(const bf16x8*)(smean + (16 + r16) * LDSPAD + kc * 32 + koff);
    ah0[kc] = *(const bf16x8*)(hrow0 + kc * 32 + koff);
    ah1[kc] = *(const bf16x8*)(hrow1 + kc * 32 + koff);
  }
  int nbase = wave * 16;
  float bias = bl[nbase + r16];
  f32x4 acc0 = {bias, bias, bias, bias};
  f32x4 acc1 = {bias, bias, bias, bias};
  const ushort* wlrow = Wlb + (size_t)(nbase + r16) * C;
  const ushort* wrrow = Wrb + (size_t)(nbase + r16) * C;
#pragma unroll
  for (int kc = 0; kc < 4; ++kc) {
    bf16x8 wl = *(const bf16x8*)(wlrow + kc * 32 + koff);
    acc0 = __builtin_amdgcn_mfma_f32_16x16x32_bf16(am0[kc], wl, acc0, 0, 0, 0);
    acc1 = __builtin_amdgcn_mfma_f32_16x16x32_bf16(am1[kc], wl, acc1, 0, 0, 0);
    bf16x8 wr = *(const bf16x8*)(wrrow + kc * 32 + koff);
    acc0 = __builtin_amdgcn_mfma_f32_16x16x32_bf16(ah0[kc], wr, acc0, 0, 0, 0);
    acc1 = __builtin_amdgcn_mfma_f32_16x16x32_bf16(ah1[kc], wr, acc1, 0, 0, 0);
  }
#pragma unroll
  for (int r = 0; r < 4; ++r) {
    int row0 = mbase + quad * 4 + r;
    if (row0 < ntgt) {
      float v = acc0[r];
      if (RELU) v = fmaxf(v, 0.f);
      if (BF16OUT)
        ((ushort*)outp)[(size_t)row0 * C + nbase + r16] = (ushort)f2bf(v);
      else
        ((float*)outp)[(size_t)row0 * C + nbase + r16] = v;
    }
    int row1 = mbase + 16 + quad * 4 + r;
    if (row1 < ntgt) {
      float v = acc1[r];
      if (RELU) v = fmaxf(v, 0.f);
      if (BF16OUT)
        ((ushort*)outp)[(size_t)row1 * C + nbase + r16] = (ushort)f2bf(v);
      else
        ((float*)outp)[(size_t)row1 * C + nbase + r16] = v;
    }
  }
}

extern "C" void kernel_launch(void* const* d_in, const int* in_sizes, int n_in,
                              void* d_out, int out_size, void* d_ws, size_t ws_size,
                              hipStream_t stream) {
  const int*   x    = (const int*)d_in[0];
  const int*   src1 = (const int*)d_in[1];
  const int*   dst1 = (const int*)d_in[2];
  const int*   src2 = (const int*)d_in[3];
  const int*   dst2 = (const int*)d_in[4];
  const float* emb  = (const float*)d_in[7];
  const float* ln_g = (const float*)d_in[8];
  const float* ln_b = (const float*)d_in[9];
  const float* Wl1  = (const float*)d_in[10];
  const float* bl1  = (const float*)d_in[11];
  const float* Wr1  = (const float*)d_in[12];
  const float* Wl2  = (const float*)d_in[13];
  const float* bl2  = (const float*)d_in[14];
  const float* Wr2  = (const float*)d_in[15];

  const int N0 = in_sizes[0] / 16;   // 100000
  const int E1 = in_sizes[1];        // 500000
  const int E2 = in_sizes[3];        // 100000
  const int N1 = 25000;
  const int N2 = 5000;
  const int LEAF_ELEMS = in_sizes[7];  // 50000*128
  const int W_ELEMS = C * C;

  char* ws = (char*)d_ws;
  size_t off = 0;
  auto alloc = [&](size_t bytes) {
    char* p = ws + off;
    off += (bytes + 255) & ~(size_t)255;
    return p;
  };
  ushort* embh   = (ushort*)alloc((size_t)LEAF_ELEMS * 2);   // 12.8 MB
  ushort* h0     = (ushort*)alloc((size_t)N0 * C * 2);       // 25.6 MB
  ushort* h1     = (ushort*)alloc((size_t)N1 * C * 2);       //  6.4 MB
  ushort* wb     = (ushort*)alloc((size_t)4 * W_ELEMS * 2);  // Wl1|Wr1|Wl2|Wr2
  int*    slots1 = (int*)alloc((size_t)N1 * CAP * 4);        //  6.4 MB
  int*    slots2 = (int*)alloc((size_t)N2 * CAP * 4);        //  1.28 MB
  char*   zbase  = ws + off;  // cnt arrays, zeroed by k_prep
  int*    cnt1   = (int*)alloc((size_t)N1 * 4);
  int*    cnt2   = (int*)alloc((size_t)N2 * 4);
  size_t  zbytes = (size_t)((ws + off) - zbase);

  float* out = (float*)d_out;
  ushort* Wl1b = wb;
  ushort* Wr1b = wb + W_ELEMS;
  ushort* Wl2b = wb + 2 * W_ELEMS;
  ushort* Wr2b = wb + 3 * W_ELEMS;

  // 1) prep: converts + cnt zeroing
  {
    int n4 = LEAF_ELEMS / 4;
    int nw4each = W_ELEMS / 4;
    int nz4 = (int)(zbytes / 16);
    k_prep<<<(n4 + 255) / 256, 256, 0, stream>>>(
        emb, (ushort4*)embh, n4,
        (const float4*)Wl1, (const float4*)Wr1, (const float4*)Wl2, (const float4*)Wr2,
        (ushort4*)wb, nw4each, (int4*)zbase, nz4);
  }

  // 2) embed + LN + ReLU with both bucket lists interleaved (Bresenham spread,
  //    512 edges per bucket block)
  {
    int bktBlocks = (E1 + E2 + 511) / 512;  // 1172
    int embBlocks = (N0 + 15) / 16;         // 6250 (4 waves x 4 nodes per block)
    int totBlocks = bktBlocks + embBlocks;  // 7422
    k_embed_bkt<<<totBlocks, 256, 0, stream>>>(
        x, embh, ln_g, ln_b, h0, N0,
        src1, dst1, cnt1, slots1, E1,
        src2, dst2, cnt2, slots2, E2, bktBlocks, totBlocks);
  }

  // 3) conv1 (aggregate + MFMA combine + ReLU) -> h1 bf16; 32 nodes/block
  k_conv<true, true><<<(N1 + 31) / 32, 512, 0, stream>>>(
      cnt1, slots1, h0, Wl1b, bl1, Wr1b, h1, N1);

  // 4) conv2 -> d_out fp32; 32 nodes/block
  k_conv<false, false><<<(N2 + 31) / 32, 512, 0, stream>>>(
      cnt2, slots2, h1, Wl2b, bl2, Wr2b, out, N2);
}

// Round 13
// 213.818 us; speedup vs baseline: 1.0191x; 1.0191x over previous
//
#include <hip/hip_runtime.h>

#define C 128
#define LDSPAD 136  // padded LDS row stride (ushorts); 272B rows, 16B-aligned
#define CAP 64      // padded-CSR slots per node (mean deg 20, Poisson tail < 1e-13)

typedef unsigned int uint;
typedef unsigned short ushort;
typedef __attribute__((ext_vector_type(8))) short bf16x8;
typedef __attribute__((ext_vector_type(4))) float f32x4;
typedef __attribute__((ext_vector_type(4))) float nf4;  // nontemporal-capable float4

__device__ __forceinline__ float bf_lo(uint u) { return __uint_as_float(u << 16); }
__device__ __forceinline__ float bf_hi(uint u) { return __uint_as_float(u & 0xffff0000u); }
__device__ __forceinline__ uint f2bf(float f) {
  uint u = __float_as_uint(f);
  return (u + 0x7fffu + ((u >> 16) & 1u)) >> 16;  // RNE, no NaN inputs
}
__device__ __forceinline__ uint pk2(float a, float b) {
  return f2bf(a) | (f2bf(b) << 16);
}

// ---------------- Kernel 1: prep — emb->bf16 (nt load), 4 weights->bf16, zero cnt ----------
__global__ __launch_bounds__(256) void k_prep(
    const float* __restrict__ emb, ushort4* __restrict__ embh, int n4,
    const float4* __restrict__ w0, const float4* __restrict__ w1,
    const float4* __restrict__ w2, const float4* __restrict__ w3,
    ushort4* __restrict__ wb, int nw4each,
    int4* __restrict__ zb, int nz4) {
  int i = blockIdx.x * blockDim.x + threadIdx.x;
  if (i < n4) {
    nf4 f = __builtin_nontemporal_load((const nf4*)emb + i);
    ushort4 o = {(ushort)f2bf(f.x), (ushort)f2bf(f.y), (ushort)f2bf(f.z), (ushort)f2bf(f.w)};
    embh[i] = o;
  }
  if (i < 4 * nw4each) {
    int m = i / nw4each;
    int j = i - m * nw4each;
    const float4* w = (m == 0) ? w0 : (m == 1) ? w1 : (m == 2) ? w2 : w3;
    float4 f = w[j];
    ushort4 o = {(ushort)f2bf(f.x), (ushort)f2bf(f.y), (ushort)f2bf(f.z), (ushort)f2bf(f.w)};
    wb[i] = o;
  }
  if (i < nz4) {
    int4 z = {0, 0, 0, 0};
    zb[i] = z;
  }
}

// LayerNorm+ReLU for ONE node over 8-channels-per-lane layout (lane c holds ch
// c*8..c*8+7, duplicated across the 4 grps) and packed uint4 store.
__device__ __forceinline__ void ln_relu_store(const float s[8], float4 ga, float4 gb,
                                              float4 ba, float4 bb, ushort* hrow, int c) {
  float loc = ((s[0] + s[1]) + (s[2] + s[3])) + ((s[4] + s[5]) + (s[6] + s[7]));
#pragma unroll
  for (int off = 8; off; off >>= 1) loc += __shfl_xor(loc, off, 64);
  float mu = loc * (1.f / C);
  float d[8];
  float sq = 0.f;
#pragma unroll
  for (int j = 0; j < 8; ++j) {
    d[j] = s[j] - mu;
    sq += d[j] * d[j];
  }
#pragma unroll
  for (int off = 8; off; off >>= 1) sq += __shfl_xor(sq, off, 64);
  float rs = rsqrtf(sq * (1.f / C) + 1e-5f);
  float o0 = fmaxf(d[0] * rs * ga.x + ba.x, 0.f);
  float o1 = fmaxf(d[1] * rs * ga.y + ba.y, 0.f);
  float o2 = fmaxf(d[2] * rs * ga.z + ba.z, 0.f);
  float o3 = fmaxf(d[3] * rs * ga.w + ba.w, 0.f);
  float o4 = fmaxf(d[4] * rs * gb.x + bb.x, 0.f);
  float o5 = fmaxf(d[5] * rs * gb.y + bb.y, 0.f);
  float o6 = fmaxf(d[6] * rs * gb.z + bb.z, 0.f);
  float o7 = fmaxf(d[7] * rs * gb.w + bb.w, 0.f);
  uint4 o = {pk2(o0, o1), pk2(o2, o3), pk2(o4, o5), pk2(o6, o7)};
  *(uint4*)(hrow + c * 8) = o;
}

// ---------------- Kernel 2: embed+LN+ReLU with INTERLEAVED bucket blocks (R10 best) -------
// Bucket blocks (both edge lists, 2 edges/thread) are Bresenham-spread among embed
// blocks so the scatter trickles into the gather's latency slack. Per-grp LN epilogue:
// after xor-16/32 reduction every lane holds all 4 node sums; grp g stores node g.
// Embed: one wave per FOUR node embedding-bags; 16 lanes x uint4 per 256B emb row.
__global__ __launch_bounds__(256) void k_embed_bkt(
    const int* __restrict__ x, const ushort* __restrict__ emb,
    const float* __restrict__ g, const float* __restrict__ b,
    ushort* __restrict__ h, int n0,
    const int* __restrict__ src1, const int* __restrict__ dst1,
    int* __restrict__ cnt1, int* __restrict__ slots1, int e1,
    const int* __restrict__ src2, const int* __restrict__ dst2,
    int* __restrict__ cnt2, int* __restrict__ slots2, int e2,
    int bktBlocks, int totBlocks) {
  uint bid = blockIdx.x;
  // Bresenham spread: f(b) = floor(b*bktBlocks/totBlocks); block b is a bucket
  // block iff f(b+1) > f(b); bucket index = f(b); embed index = b - f(b).
  uint f0 = (bid * (uint)bktBlocks) / (uint)totBlocks;
  uint f1 = ((bid + 1u) * (uint)bktBlocks) / (uint)totBlocks;
  if (f1 > f0) {
    int base = (int)f0 * 512 + (int)threadIdx.x;
#pragma unroll
    for (int r = 0; r < 2; ++r) {
      int i = base + r * 256;
      if (i < e1) {
        int d = __builtin_nontemporal_load(&dst1[i]);
        int s = __builtin_nontemporal_load(&src1[i]);
        int p = atomicAdd(&cnt1[d], 1);
        if (p < CAP) __builtin_nontemporal_store(s, &slots1[d * CAP + p]);
      } else if (i < e1 + e2) {
        int j = i - e1;
        int d = __builtin_nontemporal_load(&dst2[j]);
        int s = __builtin_nontemporal_load(&src2[j]);
        int p = atomicAdd(&cnt2[d], 1);
        if (p < CAP) __builtin_nontemporal_store(s, &slots2[d * CAP + p]);
      }
    }
    return;
  }
  int eb = (int)(bid - f0);
  int wid = threadIdx.x >> 6;
  int lane = threadIdx.x & 63;
  int grp = lane >> 4;  // 0..3: token-subgroup, later the node this lane stores
  int c = lane & 15;    // channel-16th: lane covers ch c*8..c*8+7
  int node0 = (eb * 4 + wid) * 4;  // 4 consecutive nodes per wave
  if (node0 >= n0) return;         // n0 % 16 == 0: no intra-wave tail
  int xv0 = __builtin_nontemporal_load(&x[(size_t)(node0 + 0) * 16 + c]);
  int xv1 = __builtin_nontemporal_load(&x[(size_t)(node0 + 1) * 16 + c]);
  int xv2 = __builtin_nontemporal_load(&x[(size_t)(node0 + 2) * 16 + c]);
  int xv3 = __builtin_nontemporal_load(&x[(size_t)(node0 + 3) * 16 + c]);
  float s[4][8];
#pragma unroll
  for (int n = 0; n < 4; ++n)
#pragma unroll
    for (int j = 0; j < 8; ++j) s[n][j] = 0.f;
#pragma unroll
  for (int w = 0; w < 4; ++w) {
    int t0 = __shfl(xv0, w * 4 + grp, 64);
    int t1 = __shfl(xv1, w * 4 + grp, 64);
    int t2 = __shfl(xv2, w * 4 + grp, 64);
    int t3 = __shfl(xv3, w * 4 + grp, 64);
    uint4 u0 = ((const uint4*)(emb + (size_t)t0 * C))[c];
    uint4 u1 = ((const uint4*)(emb + (size_t)t1 * C))[c];
    uint4 u2 = ((const uint4*)(emb + (size_t)t2 * C))[c];
    uint4 u3 = ((const uint4*)(emb + (size_t)t3 * C))[c];
    s[0][0] += bf_lo(u0.x); s[0][1] += bf_hi(u0.x);
    s[0][2] += bf_lo(u0.y); s[0][3] += bf_hi(u0.y);
    s[0][4] += bf_lo(u0.z); s[0][5] += bf_hi(u0.z);
    s[0][6] += bf_lo(u0.w); s[0][7] += bf_hi(u0.w);
    s[1][0] += bf_lo(u1.x); s[1][1] += bf_hi(u1.x);
    s[1][2] += bf_lo(u1.y); s[1][3] += bf_hi(u1.y);
    s[1][4] += bf_lo(u1.z); s[1][5] += bf_hi(u1.z);
    s[1][6] += bf_lo(u1.w); s[1][7] += bf_hi(u1.w);
    s[2][0] += bf_lo(u2.x); s[2][1] += bf_hi(u2.x);
    s[2][2] += bf_lo(u2.y); s[2][3] += bf_hi(u2.y);
    s[2][4] += bf_lo(u2.z); s[2][5] += bf_hi(u2.z);
    s[2][6] += bf_lo(u2.w); s[2][7] += bf_hi(u2.w);
    s[3][0] += bf_lo(u3.x); s[3][1] += bf_hi(u3.x);
    s[3][2] += bf_lo(u3.y); s[3][3] += bf_hi(u3.y);
    s[3][4] += bf_lo(u3.z); s[3][5] += bf_hi(u3.z);
    s[3][6] += bf_lo(u3.w); s[3][7] += bf_hi(u3.w);
  }
  // combine the 4 token-subgroups: every lane ends with all 4 nodes' full sums
#pragma unroll
  for (int n = 0; n < 4; ++n)
#pragma unroll
    for (int j = 0; j < 8; ++j) {
      s[n][j] += __shfl_xor(s[n][j], 16, 64);
      s[n][j] += __shfl_xor(s[n][j], 32, 64);
    }
  // per-grp epilogue: grp g handles node g (static ?: selection — rule #20)
  float sel[8];
#pragma unroll
  for (int j = 0; j < 8; ++j)
    sel[j] = (grp == 0) ? s[0][j] : (grp == 1) ? s[1][j] : (grp == 2) ? s[2][j] : s[3][j];
  float4 ga = ((const float4*)g)[c * 2];
  float4 gb = ((const float4*)g)[c * 2 + 1];
  float4 ba = ((const float4*)b)[c * 2];
  float4 bb = ((const float4*)b)[c * 2 + 1];
  ln_relu_store(sel, ga, gb, ba, bb, h + (size_t)(node0 + grp) * C, c);
}

// ---------------- Kernel 3/4: fused conv = aggregate(mean) + MFMA combine (R5 best) -------
// block = 512 (8 waves) -> 16 target nodes.
// Phase A: each HALF-wave aggregates one node; edge ids in registers (<=64 via CAP);
//          16 lanes x uint4 per row -> 2 edges per load instruction per half-wave.
//          Unconditional loads + value-mask (R7: predication breaks load clauses;
//          R8: explicit SW pipelining neutral; R11: 32-node batching neutral).
// Phase B: wave w computes output n-tile w: 8 MFMAs (mean@Wl + h@Wr), bias in acc.
// C/D layout: lane,reg -> out[mbase + (lane>>4)*4 + reg][nbase + (lane&15)]  [m89-verified]
template <bool RELU, bool BF16OUT>
__global__ __launch_bounds__(512) void k_conv(
    const int* __restrict__ cntArr, const int* __restrict__ slots,
    const ushort* __restrict__ h, const ushort* __restrict__ Wlb,
    const float* __restrict__ bl, const ushort* __restrict__ Wrb,
    void* __restrict__ outp, int ntgt) {
  __shared__ __align__(16) ushort smean[16 * LDSPAD];
  int wave = threadIdx.x >> 6;
  int lane = threadIdx.x & 63;
  int grp = lane >> 5, sub = lane & 31;
  int mbase = blockIdx.x * 16;
  int nl = wave * 2 + grp;
  int node = mbase + nl;

  // ---- Phase A ----
  int truecnt = (node < ntgt) ? cntArr[node] : 0;
  int cnt = min(truecnt, CAP);
  const int* sl = slots + (size_t)(node < ntgt ? node : 0) * CAP;
  int ev = (sub < cnt) ? sl[sub] : 0;
  int ev2 = (sub + 32 < cnt) ? sl[sub + 32] : 0;
  int dmax = max(cnt, __shfl_xor(cnt, 32, 64));
  int half = grp * 32;
  int l16 = (lane >> 4) & 1;  // which 16-lane group within the half-wave
  int c = lane & 15;          // lane covers ch c*8..c*8+7 of its edge's row
  float s[8];
#pragma unroll
  for (int j = 0; j < 8; ++j) s[j] = 0.f;
  for (int d = 0; d < dmax; d += 8) {
#pragma unroll
    for (int k = 0; k < 4; ++k) {
      int p = d + 2 * k + l16;
      int e = (p < 32) ? __shfl(ev, half + p, 64) : __shfl(ev2, half + p - 32, 64);
      uint4 u = ((const uint4*)(h + (size_t)e * C))[c];
      uint msk = (p < cnt) ? 0xffffffffu : 0u;
      u.x &= msk; u.y &= msk; u.z &= msk; u.w &= msk;
      s[0] += bf_lo(u.x); s[1] += bf_hi(u.x);
      s[2] += bf_lo(u.y); s[3] += bf_hi(u.y);
      s[4] += bf_lo(u.z); s[5] += bf_hi(u.z);
      s[6] += bf_lo(u.w); s[7] += bf_hi(u.w);
    }
  }
  // combine the two 16-lane halves (each summed a disjoint set of edges)
#pragma unroll
  for (int j = 0; j < 8; ++j) s[j] += __shfl_xor(s[j], 16, 64);
  float sc = 1.f / (float)max(truecnt, 1);
  uint4 o = {pk2(s[0] * sc, s[1] * sc), pk2(s[2] * sc, s[3] * sc),
             pk2(s[4] * sc, s[5] * sc), pk2(s[6] * sc, s[7] * sc)};
  if (l16 == 0) *(uint4*)(smean + nl * LDSPAD + c * 8) = o;
  __syncthreads();

  // ---- Phase B ----
  int r16 = lane & 15;
  int quad = lane >> 4;
  int koff = quad * 8;
  bf16x8 am[4], ah[4];
  int hr = min(mbase + r16, ntgt - 1);
  const ushort* hrow = h + (size_t)hr * C;
#pragma unroll
  for (int kc = 0; kc < 4; ++kc) {
    am[kc] = *(const bf16x8*)(smean + r16 * LDSPAD + kc * 32 + koff);
    ah[kc] = *(const bf16x8*)(hrow + kc * 32 + koff);
  }
  int nbase = wave * 16;
  float bias = bl[nbase + r16];
  f32x4 acc = {bias, bias, bias, bias};
  const ushort* wlrow = Wlb + (size_t)(nbase + r16) * C;
  const ushort* wrrow = Wrb + (size_t)(nbase + r16) * C;
#pragma unroll
  for (int kc = 0; kc < 4; ++kc) {
    bf16x8 wl = *(const bf16x8*)(wlrow + kc * 32 + koff);
    acc = __builtin_amdgcn_mfma_f32_16x16x32_bf16(am[kc], wl, acc, 0, 0, 0);
    bf16x8 wr = *(const bf16x8*)(wrrow + kc * 32 + koff);
    acc = __builtin_amdgcn_mfma_f32_16x16x32_bf16(ah[kc], wr, acc, 0, 0, 0);
  }
#pragma unroll
  for (int r = 0; r < 4; ++r) {
    int row = mbase + quad * 4 + r;
    if (row < ntgt) {
      float v = acc[r];
      if (RELU) v = fmaxf(v, 0.f);
      if (BF16OUT)
        ((ushort*)outp)[(size_t)row * C + nbase + r16] = (ushort)f2bf(v);
      else
        ((float*)outp)[(size_t)row * C + nbase + r16] = v;
    }
  }
}

extern "C" void kernel_launch(void* const* d_in, const int* in_sizes, int n_in,
                              void* d_out, int out_size, void* d_ws, size_t ws_size,
                              hipStream_t stream) {
  const int*   x    = (const int*)d_in[0];
  const int*   src1 = (const int*)d_in[1];
  const int*   dst1 = (const int*)d_in[2];
  const int*   src2 = (const int*)d_in[3];
  const int*   dst2 = (const int*)d_in[4];
  const float* emb  = (const float*)d_in[7];
  const float* ln_g = (const float*)d_in[8];
  const float* ln_b = (const float*)d_in[9];
  const float* Wl1  = (const float*)d_in[10];
  const float* bl1  = (const float*)d_in[11];
  const float* Wr1  = (const float*)d_in[12];
  const float* Wl2  = (const float*)d_in[13];
  const float* bl2  = (const float*)d_in[14];
  const float* Wr2  = (const float*)d_in[15];

  const int N0 = in_sizes[0] / 16;   // 100000
  const int E1 = in_sizes[1];        // 500000
  const int E2 = in_sizes[3];        // 100000
  const int N1 = 25000;
  const int N2 = 5000;
  const int LEAF_ELEMS = in_sizes[7];  // 50000*128
  const int W_ELEMS = C * C;

  char* ws = (char*)d_ws;
  size_t off = 0;
  auto alloc = [&](size_t bytes) {
    char* p = ws + off;
    off += (bytes + 255) & ~(size_t)255;
    return p;
  };
  ushort* embh   = (ushort*)alloc((size_t)LEAF_ELEMS * 2);   // 12.8 MB
  ushort* h0     = (ushort*)alloc((size_t)N0 * C * 2);       // 25.6 MB
  ushort* h1     = (ushort*)alloc((size_t)N1 * C * 2);       //  6.4 MB
  ushort* wb     = (ushort*)alloc((size_t)4 * W_ELEMS * 2);  // Wl1|Wr1|Wl2|Wr2
  int*    slots1 = (int*)alloc((size_t)N1 * CAP * 4);        //  6.4 MB
  int*    slots2 = (int*)alloc((size_t)N2 * CAP * 4);        //  1.28 MB
  char*   zbase  = ws + off;  // cnt arrays, zeroed by k_prep
  int*    cnt1   = (int*)alloc((size_t)N1 * 4);
  int*    cnt2   = (int*)alloc((size_t)N2 * 4);
  size_t  zbytes = (size_t)((ws + off) - zbase);

  float* out = (float*)d_out;
  ushort* Wl1b = wb;
  ushort* Wr1b = wb + W_ELEMS;
  ushort* Wl2b = wb + 2 * W_ELEMS;
  ushort* Wr2b = wb + 3 * W_ELEMS;

  // 1) prep: converts + cnt zeroing
  {
    int n4 = LEAF_ELEMS / 4;
    int nw4each = W_ELEMS / 4;
    int nz4 = (int)(zbytes / 16);
    k_prep<<<(n4 + 255) / 256, 256, 0, stream>>>(
        emb, (ushort4*)embh, n4,
        (const float4*)Wl1, (const float4*)Wr1, (const float4*)Wl2, (const float4*)Wr2,
        (ushort4*)wb, nw4each, (int4*)zbase, nz4);
  }

  // 2) embed + LN + ReLU with both bucket lists interleaved (Bresenham spread,
  //    512 edges per bucket block)
  {
    int bktBlocks = (E1 + E2 + 511) / 512;  // 1172
    int embBlocks = (N0 + 15) / 16;         // 6250 (4 waves x 4 nodes per block)
    int totBlocks = bktBlocks + embBlocks;  // 7422
    k_embed_bkt<<<totBlocks, 256, 0, stream>>>(
        x, embh, ln_g, ln_b, h0, N0,
        src1, dst1, cnt1, slots1, E1,
        src2, dst2, cnt2, slots2, E2, bktBlocks, totBlocks);
  }

  // 3) conv1 (aggregate + MFMA combine + ReLU) -> h1 bf16
  k_conv<true, true><<<(N1 + 15) / 16, 512, 0, stream>>>(
      cnt1, slots1, h0, Wl1b, bl1, Wr1b, h1, N1);

  // 4) conv2 -> d_out fp32
  k_conv<false, false><<<(N2 + 15) / 16, 512, 0, stream>>>(
      cnt2, slots2, h1, Wl2b, bl2, Wr2b, out, N2);
}